// Round 6
// baseline (328.802 us; speedup 1.0000x reference)
//
#include <hip/hip_runtime.h>
#include <hip/hip_bf16.h>
#include <stdint.h>

#define N_NODES 100000
#define D_FEAT  128
#define RSH     6                                 // log2(RPB)
#define RPB     64                                // rows per bucket
#define NBUCK   ((N_NODES + RPB - 1) / RPB)       // 1563
#define OCAP    8192                              // overflow list capacity
#define SC_THR  1024
#define SC_EPT  16
#define SC_TILE (SC_THR * SC_EPT)                 // 16384 edges per scatter WG
#define COLMASK 0x1FFFF

__device__ __forceinline__ uint32_t bf16_rne(float x) {
    uint32_t u = __float_as_uint(x);
    return (u + 0x7FFFu + ((u >> 16) & 1u)) >> 16;
}

// ---------- Phase 1 (fused): batched scatter into line-aligned slabs + fp32->bf16 conv ----
// Blocks [0, scb): scatter. Each WG ranks 16384 edges by bucket in LDS, reserves a
// contiguous LINE-ALIGNED range per bucket (PAD: round batch to 8 records = 64 B),
// writes real records + inert (0,0,val=0) pad records. Every rec line has exactly one
// writer WG (one XCD) -> streaming full-line writes, no cross-XCD partial-line ping-pong.
// Blocks [scb, grid): grid-stride fp32 -> packed-bf16 conversion of embeds.
template <int CAPF_, bool PAD, bool CONV>
__global__ __launch_bounds__(SC_THR) void scatter_conv_kernel(
    const int* __restrict__ row, const int* __restrict__ col,
    const float* __restrict__ val, int* __restrict__ cursor,
    int2* __restrict__ rec, int4* __restrict__ oflow, int* __restrict__ ocnt,
    const float4* __restrict__ embf, uint2* __restrict__ embbf,
    int n, int scb, int n4)
{
    if (CONV && (int)blockIdx.x >= scb) {
        const int nb = gridDim.x - scb;
        const int stride = nb * SC_THR;
        for (int i = (blockIdx.x - scb) * SC_THR + threadIdx.x; i < n4; i += stride) {
            float4 f = embf[i];
            embbf[i] = make_uint2(bf16_rne(f.x) | (bf16_rne(f.y) << 16),
                                  bf16_rne(f.z) | (bf16_rne(f.w) << 16));
        }
        return;
    }

    __shared__ int cnt[NBUCK];
    __shared__ int base[NBUCK];
    const int tid = threadIdx.x;
    const int e0  = blockIdx.x * SC_TILE + tid * SC_EPT;   // 16 consecutive edges/thread

    for (int i = tid; i < NBUCK; i += SC_THR) cnt[i] = 0;
    __syncthreads();

    int   r[SC_EPT], c[SC_EPT];
    float v[SC_EPT];
    if (e0 + SC_EPT <= n) {
        const int4* rp = (const int4*)(row + e0);
        const int4* cp = (const int4*)(col + e0);
        const float4* vp = (const float4*)(val + e0);
        #pragma unroll
        for (int q = 0; q < SC_EPT / 4; q++) {
            int4 rr = rp[q]; int4 cc = cp[q]; float4 vv = vp[q];
            r[q*4+0]=rr.x; r[q*4+1]=rr.y; r[q*4+2]=rr.z; r[q*4+3]=rr.w;
            c[q*4+0]=cc.x; c[q*4+1]=cc.y; c[q*4+2]=cc.z; c[q*4+3]=cc.w;
            v[q*4+0]=vv.x; v[q*4+1]=vv.y; v[q*4+2]=vv.z; v[q*4+3]=vv.w;
        }
    } else {
        #pragma unroll
        for (int k = 0; k < SC_EPT; k++) {
            int e = e0 + k;
            if (e < n) { r[k] = row[e]; c[k] = col[e]; v[k] = val[e]; }
            else       { r[k] = -1; }
        }
    }

    int rk[SC_EPT];
    #pragma unroll
    for (int k = 0; k < SC_EPT; k++)
        if (r[k] >= 0) rk[k] = atomicAdd(&cnt[r[k] >> RSH], 1);
    __syncthreads();

    for (int i = tid; i < NBUCK; i += SC_THR) {
        int cc = cnt[i];
        if (cc) {
            int padded = PAD ? ((cc + 7) & ~7) : cc;
            int b0 = atomicAdd(&cursor[i], padded);
            base[i] = b0;
            if (PAD) {
                int2* slab = rec + (size_t)i * CAPF_;
                for (int p = cc; p < padded; ++p) {
                    int pos = b0 + p;
                    if (pos < CAPF_) slab[pos] = make_int2(0, 0);  // row 0, col 0, val 0.0
                }
            }
        }
    }
    __syncthreads();

    #pragma unroll
    for (int k = 0; k < SC_EPT; k++) {
        if (r[k] >= 0) {
            int bk  = r[k] >> RSH;
            int pos = base[bk] + rk[k];
            if (pos < CAPF_) {
                rec[(size_t)bk * CAPF_ + pos] =
                    make_int2(((r[k] & (RPB - 1)) << 17) | c[k], __float_as_int(v[k]));
            } else {
                int op = atomicAdd(ocnt, 1);
                if (op < OCAP) oflow[op] = make_int4(r[k], c[k], __float_as_int(v[k]), 0);
            }
        }
    }
}

// ---------- Phase 2: fused in-LDS row sort + SpMM, one WG (512 thr) per bucket ----------
template <bool BF16, int CAPF_>
__global__ __launch_bounds__(512) void spmm_fixed_kernel(const int* __restrict__ fill,
                                                         const int2* __restrict__ rec,
                                                         const void* __restrict__ emb,
                                                         float* __restrict__ out)
{
    constexpr int KMAX = (CAPF_ + 511) / 512;
    __shared__ int2 buf[CAPF_];
    __shared__ int  cnt[RPB];
    __shared__ int  start[RPB];
    __shared__ int  sc_[RPB];

    const int tid  = threadIdx.x;
    const int lane = tid & 63;
    const int wv   = tid >> 6;                    // 0..7
    const int b    = blockIdx.x;
    const int m    = min(fill[b], CAPF_);
    const int rows = min(RPB, N_NODES - b * RPB);
    const size_t beg = (size_t)b * CAPF_;
    const uint32_t* __restrict__ embu = (const uint32_t*)emb;
    const float2*   __restrict__ emb2 = (const float2*)emb;

    if (tid < RPB) cnt[tid] = 0;
    __syncthreads();

    int2 rc[KMAX];
    int  rk[KMAX];
    #pragma unroll
    for (int k = 0; k < KMAX; k++) {
        int i = k * 512 + tid;
        if (i < m) {
            rc[k] = rec[beg + i];
            rk[k] = atomicAdd(&cnt[rc[k].x >> 17], 1);
        }
    }
    __syncthreads();
    if (tid < RPB) sc_[tid] = cnt[tid];
    __syncthreads();
    for (int off = 1; off < RPB; off <<= 1) {
        int t = 0;
        if (tid < RPB && tid >= off) t = sc_[tid - off];
        __syncthreads();
        if (tid < RPB) sc_[tid] += t;
        __syncthreads();
    }
    if (tid < RPB) start[tid] = sc_[tid] - cnt[tid];
    __syncthreads();
    #pragma unroll
    for (int k = 0; k < KMAX; k++) {
        int i = k * 512 + tid;
        if (i < m) buf[start[rc[k].x >> 17] + rk[k]] = rc[k];
    }
    __syncthreads();

    // 8 waves x 8 rows each; records row-grouped in LDS (broadcast reads)
    for (int rl = wv * 8; rl < wv * 8 + 8; rl++) {
        const int s0 = start[rl];
        const int c0 = cnt[rl];
        float ax = 0.f, ay = 0.f;
        int j = 0;
        for (; j + 8 <= c0; j += 8) {             // 8 gathers in flight
            int2 e[8];
            #pragma unroll
            for (int q = 0; q < 8; q++) e[q] = buf[s0 + j + q];
            float mx[8], my[8], vv[8];
            #pragma unroll
            for (int q = 0; q < 8; q++) {
                int cc = e[q].x & COLMASK;
                vv[q] = __int_as_float(e[q].y);
                if (BF16) {
                    uint32_t u = embu[(size_t)cc * 64 + lane];
                    mx[q] = __uint_as_float(u << 16);
                    my[q] = __uint_as_float(u & 0xFFFF0000u);
                } else {
                    float2 mm = emb2[(size_t)cc * 64 + lane];
                    mx[q] = mm.x; my[q] = mm.y;
                }
            }
            #pragma unroll
            for (int q = 0; q < 8; q++) { ax += vv[q] * mx[q]; ay += vv[q] * my[q]; }
        }
        for (; j < c0; j++) {
            int2 e = buf[s0 + j];
            int cc = e.x & COLMASK;
            float vv = __int_as_float(e.y);
            float mx, my;
            if (BF16) {
                uint32_t u = embu[(size_t)cc * 64 + lane];
                mx = __uint_as_float(u << 16);
                my = __uint_as_float(u & 0xFFFF0000u);
            } else {
                float2 mm = emb2[(size_t)cc * 64 + lane];
                mx = mm.x; my = mm.y;
            }
            ax += vv * mx; ay += vv * my;
        }
        if (rl < rows) {
            float2* o = (float2*)(out + (size_t)(b * RPB + rl) * D_FEAT);
            o[lane] = make_float2(ax, ay);        // every row written (zeros if deg 0)
        }
    }
}

// ---------- Phase 3: overflow fixup (statistically ~0 edges) ----------
__global__ __launch_bounds__(256) void oflow_kernel(const int4* __restrict__ oflow,
                                                    const int* __restrict__ ocnt,
                                                    const float* __restrict__ embeds,
                                                    float* __restrict__ out) {
    const int nof  = min(*ocnt, OCAP);
    const int lane = threadIdx.x & 63;
    const int w    = (blockIdx.x * 256 + threadIdx.x) >> 6;
    const int nw   = (gridDim.x * 256) >> 6;
    for (int i = w; i < nof; i += nw) {
        int4 e = oflow[i];
        const float2* src = (const float2*)(embeds + (size_t)e.y * D_FEAT);
        float2 mm = src[lane];
        float vv = __int_as_float(e.z);
        float* dst = out + (size_t)e.x * D_FEAT + (lane << 1);
        unsafeAtomicAdd(dst,     vv * mm.x);
        unsafeAtomicAdd(dst + 1, vv * mm.y);
    }
}

// ---------- Last-resort fallback (ws too small): atomic scatter ----------
__global__ __launch_bounds__(256) void spmm_atomic_kernel(
    const int* __restrict__ edge_row, const int* __restrict__ edge_col,
    const float* __restrict__ edge_val, const float* __restrict__ embeds,
    float* __restrict__ out, int n_edges)
{
    const int lane    = threadIdx.x & 63;
    const int wave_id = (blockIdx.x * blockDim.x + threadIdx.x) >> 6;
    const int n_waves = (gridDim.x * blockDim.x) >> 6;
    for (int e = wave_id; e < n_edges; e += n_waves) {
        const int   rr = edge_row[e];
        const int   cc = edge_col[e];
        const float vv = edge_val[e];
        const float2* src = (const float2*)(embeds + (size_t)cc * D_FEAT);
        float2 mm = src[lane];
        float* dst = out + (size_t)rr * D_FEAT + (lane << 1);
        unsafeAtomicAdd(dst,     vv * mm.x);
        unsafeAtomicAdd(dst + 1, vv * mm.y);
    }
}

static inline size_t align256(size_t x) { return (x + 255) & ~(size_t)255; }

extern "C" void kernel_launch(void* const* d_in, const int* in_sizes, int n_in,
                              void* d_out, int out_size, void* d_ws, size_t ws_size,
                              hipStream_t stream) {
    const int*   edge_row = (const int*)d_in[0];
    const int*   edge_col = (const int*)d_in[1];
    const float* edge_val = (const float*)d_in[2];
    const float* embeds   = (const float*)d_in[3];
    float*       out      = (float*)d_out;

    const int n_edges = in_sizes[0];
    const int scb = (n_edges + SC_TILE - 1) / SC_TILE;     // 196
    const int n4  = N_NODES * (D_FEAT / 4);                // 3.2M float4 -> uint2

    // Workspace layouts (rec slab sized per tier)
    const size_t sz_cur   = align256((size_t)(NBUCK + 1) * 4);
    const size_t sz_oflow = align256((size_t)OCAP * 16);
    const size_t sz_rec_p = align256((size_t)NBUCK * 3072 * 8);  // 38.4 MB (padded tier)
    const size_t sz_rec_c = align256((size_t)NBUCK * 2304 * 8);  // 28.8 MB (compact tier)
    const size_t sz_emb   = align256((size_t)N_NODES * 64 * 4);  // 25.6 MB

    const size_t need_pad  = sz_cur + sz_oflow + sz_rec_p + sz_emb;  // ~64.2 MB
    const size_t need_comp = sz_cur + sz_oflow + sz_rec_c + sz_emb;  // ~54.5 MB (round-4-proven)
    const size_t need_fp32 = sz_cur + sz_oflow + sz_rec_c;           // ~28.9 MB

    if (ws_size < need_fp32) {
        hipMemsetAsync(out, 0, (size_t)out_size * sizeof(float), stream);
        spmm_atomic_kernel<<<dim3(4096), dim3(256), 0, stream>>>(
            edge_row, edge_col, edge_val, embeds, out, n_edges);
        return;
    }

    char* ws = (char*)d_ws;
    int*  cursor = (int*)ws;                       // [NBUCK] fills; +NBUCK = ocnt
    int*  ocnt   = cursor + NBUCK;
    int4* oflow  = (int4*)(ws + sz_cur);

    hipMemsetAsync(cursor, 0, (size_t)(NBUCK + 1) * 4, stream);

    if (ws_size >= need_pad) {
        int2*     rec   = (int2*)(ws + sz_cur + sz_oflow);
        uint32_t* embbf = (uint32_t*)(ws + sz_cur + sz_oflow + sz_rec_p);
        scatter_conv_kernel<3072, true, true><<<dim3(scb * 2), dim3(SC_THR), 0, stream>>>(
            edge_row, edge_col, edge_val, cursor, rec, oflow, ocnt,
            (const float4*)embeds, (uint2*)embbf, n_edges, scb, n4);
        spmm_fixed_kernel<true, 3072><<<dim3(NBUCK), dim3(512), 0, stream>>>(
            cursor, rec, embbf, out);
    } else if (ws_size >= need_comp) {
        int2*     rec   = (int2*)(ws + sz_cur + sz_oflow);
        uint32_t* embbf = (uint32_t*)(ws + sz_cur + sz_oflow + sz_rec_c);
        scatter_conv_kernel<2304, false, true><<<dim3(scb * 2), dim3(SC_THR), 0, stream>>>(
            edge_row, edge_col, edge_val, cursor, rec, oflow, ocnt,
            (const float4*)embeds, (uint2*)embbf, n_edges, scb, n4);
        spmm_fixed_kernel<true, 2304><<<dim3(NBUCK), dim3(512), 0, stream>>>(
            cursor, rec, embbf, out);
    } else {
        int2* rec = (int2*)(ws + sz_cur + sz_oflow);
        scatter_conv_kernel<2304, false, false><<<dim3(scb), dim3(SC_THR), 0, stream>>>(
            edge_row, edge_col, edge_val, cursor, rec, oflow, ocnt,
            (const float4*)embeds, (uint2*)nullptr, n_edges, scb, n4);
        spmm_fixed_kernel<false, 2304><<<dim3(NBUCK), dim3(512), 0, stream>>>(
            cursor, rec, embeds, out);
    }
    oflow_kernel<<<dim3(16), dim3(256), 0, stream>>>(oflow, ocnt, embeds, out);
}

// Round 7
// 304.903 us; speedup vs baseline: 1.0784x; 1.0784x over previous
//
#include <hip/hip_runtime.h>
#include <hip/hip_bf16.h>
#include <stdint.h>

#define N_NODES 100000
#define D_FEAT  128
#define RPB     32                         // rows per fine bucket
#define RSH     5
#define SBSH    10                         // 1024 rows per super-bucket
#define SBROWS  1024
#define NSUP    98                         // ceil(100000/1024)
#define NBUCKR  3125                       // 100000/32 (mid-tier fine bins)
#define NBUCKF  3136                       // NSUP*32 (fast-tier fine bins incl. empties)
#define SEGA    208                        // pass-A (WG,super) segment capacity (mean 167 + 3.2 sigma)
#define REGF    320                        // pass-B (WG,bin) region capacity (mean 256 + 4 sigma)
#define NREG    4                          // pass-B slices per super-bucket
#define CAPFF   (NREG*REGF)                // 1280 records per fine bucket (fast tier)
#define CAPFM   1152                       // fine-bucket capacity (mid tier, round-5-proven)
#define OCAP    8192
#define SC_THR  1024
#define SC_EPT  16
#define SC_TILE (SC_THR*SC_EPT)            // 16384 edges per pass-A WG
#define COLMASK 0x1FFFF

__device__ __forceinline__ uint32_t bf16_rne(float x) {
    uint32_t u = __float_as_uint(x);
    return (u + 0x7FFFu + ((u >> 16) & 1u)) >> 16;
}

// ============ Pass A: edges -> 98 super-buckets, WG-exclusive segments ============
// No global reservation atomics. WG w's records for super-bucket sb go to
// recA[sb*capa + w*SEGA + rank], rank from an LDS atomic. Segments are
// single-writer (one WG, one XCD), L2-resident while hot.
// Blocks >= scb do the fp32->bf16 embeds conversion (fused).
template <bool CONV>
__global__ __launch_bounds__(SC_THR) void passA_kernel(
    const int* __restrict__ row, const int* __restrict__ col,
    const float* __restrict__ val, int* __restrict__ cntA,
    int2* __restrict__ recA, int4* __restrict__ oflow, int* __restrict__ ocnt,
    const float4* __restrict__ embf, uint2* __restrict__ embbf,
    int n, int scb, int capa, int n4)
{
    if (CONV && (int)blockIdx.x >= scb) {
        const int nb = gridDim.x - scb;
        for (int i = (blockIdx.x - scb) * SC_THR + threadIdx.x; i < n4; i += nb * SC_THR) {
            float4 f = embf[i];
            embbf[i] = make_uint2(bf16_rne(f.x) | (bf16_rne(f.y) << 16),
                                  bf16_rne(f.z) | (bf16_rne(f.w) << 16));
        }
        return;
    }

    __shared__ int cnt[NSUP];
    const int tid = threadIdx.x;
    const int w   = blockIdx.x;
    for (int i = tid; i < NSUP; i += SC_THR) cnt[i] = 0;
    __syncthreads();

    const int e0 = w * SC_TILE + tid * SC_EPT;
    #pragma unroll
    for (int qq = 0; qq < SC_EPT / 4; qq++) {
        const int e = e0 + qq * 4;
        int r[4]; int c[4]; float v[4];
        if (e + 4 <= n) {
            int4 rr = *(const int4*)(row + e);
            int4 cc = *(const int4*)(col + e);
            float4 vv = *(const float4*)(val + e);
            r[0]=rr.x; r[1]=rr.y; r[2]=rr.z; r[3]=rr.w;
            c[0]=cc.x; c[1]=cc.y; c[2]=cc.z; c[3]=cc.w;
            v[0]=vv.x; v[1]=vv.y; v[2]=vv.z; v[3]=vv.w;
        } else {
            #pragma unroll
            for (int j = 0; j < 4; j++) {
                if (e + j < n) { r[j] = row[e+j]; c[j] = col[e+j]; v[j] = val[e+j]; }
                else r[j] = -1;
            }
        }
        #pragma unroll
        for (int j = 0; j < 4; j++) {
            if (r[j] >= 0) {
                const int sb = r[j] >> SBSH;
                const int rk = atomicAdd(&cnt[sb], 1);
                if (rk < SEGA) {
                    recA[(size_t)sb * capa + w * SEGA + rk] =
                        make_int2(((r[j] & (SBROWS - 1)) << 17) | c[j], __float_as_int(v[j]));
                } else {
                    int op = atomicAdd(ocnt, 1);
                    if (op < OCAP) oflow[op] = make_int4(r[j], c[j], __float_as_int(v[j]), 0);
                }
            }
        }
    }
    __syncthreads();
    for (int i = tid; i < NSUP; i += SC_THR) cntA[i * scb + w] = min(cnt[i], SEGA);
}

// ============ Pass B: super-bucket segments -> 32 fine slabs, exclusive regions ====
// WG (sb,q) reads its ~49 segments and writes region q of each fine bucket.
// 4 segments processed concurrently (256 threads each); rank from LDS atomic.
__global__ __launch_bounds__(1024) void passB_kernel(
    const int* __restrict__ cntA, const int2* __restrict__ recA,
    int* __restrict__ fillF, int2* __restrict__ recF,
    int4* __restrict__ oflow, int* __restrict__ ocnt,
    int scb, int capa, int spq)
{
    __shared__ int cntB[32];
    __shared__ int segc[64];
    const int tid = threadIdx.x;
    const int sb  = blockIdx.x >> 2;
    const int q   = blockIdx.x & 3;
    const int s0  = q * spq;
    const int sq  = min(spq, scb - s0);
    if (tid < 32) cntB[tid] = 0;
    if (tid < sq) segc[tid] = cntA[sb * scb + s0 + tid];
    __syncthreads();

    const int sg = tid >> 8;                  // 4 concurrent segments
    const int p  = tid & 255;                 // SEGA(208) <= 256
    for (int it = 0; it * 4 < sq; it++) {
        const int s = it * 4 + sg;
        if (s < sq && p < segc[s]) {
            int2 rcd = recA[(size_t)sb * capa + (size_t)(s0 + s) * SEGA + p];
            const int rl10 = rcd.x >> 17;
            const int bkl  = rl10 >> RSH;
            const int rk   = atomicAdd(&cntB[bkl], 1);
            const int bkg  = sb * 32 + bkl;
            if (rk < REGF) {
                recF[(size_t)bkg * CAPFF + q * REGF + rk] =
                    make_int2(((rl10 & (RPB - 1)) << 17) | (rcd.x & COLMASK), rcd.y);
            } else {
                int op = atomicAdd(ocnt, 1);
                if (op < OCAP)
                    oflow[op] = make_int4(sb * SBROWS + rl10, rcd.x & COLMASK, rcd.y, 0);
            }
        }
    }
    __syncthreads();
    if (tid < 32) fillF[(sb * 32 + tid) * NREG + q] = min(cntB[tid], REGF);
}

// ============ Mid-tier single-pass scatter (round-5-proven) + fused conv ==========
template <bool CONV>
__global__ __launch_bounds__(SC_THR) void scatter_mid_kernel(
    const int* __restrict__ row, const int* __restrict__ col,
    const float* __restrict__ val, int* __restrict__ cursor,
    int2* __restrict__ rec, int4* __restrict__ oflow, int* __restrict__ ocnt,
    const float4* __restrict__ embf, uint2* __restrict__ embbf,
    int n, int scb, int n4)
{
    if (CONV && (int)blockIdx.x >= scb) {
        const int nb = gridDim.x - scb;
        for (int i = (blockIdx.x - scb) * SC_THR + threadIdx.x; i < n4; i += nb * SC_THR) {
            float4 f = embf[i];
            embbf[i] = make_uint2(bf16_rne(f.x) | (bf16_rne(f.y) << 16),
                                  bf16_rne(f.z) | (bf16_rne(f.w) << 16));
        }
        return;
    }
    __shared__ int cnt[NBUCKR];
    __shared__ int base[NBUCKR];
    const int tid = threadIdx.x;
    const int e0  = blockIdx.x * SC_TILE + tid * SC_EPT;
    for (int i = tid; i < NBUCKR; i += SC_THR) cnt[i] = 0;
    __syncthreads();

    int r[SC_EPT], c[SC_EPT]; float v[SC_EPT];
    if (e0 + SC_EPT <= n) {
        const int4* rp = (const int4*)(row + e0);
        const int4* cp = (const int4*)(col + e0);
        const float4* vp = (const float4*)(val + e0);
        #pragma unroll
        for (int q = 0; q < SC_EPT / 4; q++) {
            int4 rr = rp[q]; int4 cc = cp[q]; float4 vv = vp[q];
            r[q*4+0]=rr.x; r[q*4+1]=rr.y; r[q*4+2]=rr.z; r[q*4+3]=rr.w;
            c[q*4+0]=cc.x; c[q*4+1]=cc.y; c[q*4+2]=cc.z; c[q*4+3]=cc.w;
            v[q*4+0]=vv.x; v[q*4+1]=vv.y; v[q*4+2]=vv.z; v[q*4+3]=vv.w;
        }
    } else {
        #pragma unroll
        for (int k = 0; k < SC_EPT; k++) {
            int e = e0 + k;
            if (e < n) { r[k] = row[e]; c[k] = col[e]; v[k] = val[e]; }
            else r[k] = -1;
        }
    }
    int rk[SC_EPT];
    #pragma unroll
    for (int k = 0; k < SC_EPT; k++)
        if (r[k] >= 0) rk[k] = atomicAdd(&cnt[r[k] >> RSH], 1);
    __syncthreads();
    for (int i = tid; i < NBUCKR; i += SC_THR) {
        int cc = cnt[i];
        if (cc) base[i] = atomicAdd(&cursor[i], cc);
    }
    __syncthreads();
    #pragma unroll
    for (int k = 0; k < SC_EPT; k++) {
        if (r[k] >= 0) {
            int bk = r[k] >> RSH;
            int pos = base[bk] + rk[k];
            if (pos < CAPFM) {
                rec[(size_t)bk * CAPFM + pos] =
                    make_int2(((r[k] & (RPB - 1)) << 17) | c[k], __float_as_int(v[k]));
            } else {
                int op = atomicAdd(ocnt, 1);
                if (op < OCAP) oflow[op] = make_int4(r[k], c[k], __float_as_int(v[k]), 0);
            }
        }
    }
}

// ============ SpMM: in-LDS row sort + register accumulate, 1 WG per fine bucket ====
template <bool BF16, int NREG_, int REGF_>
__global__ __launch_bounds__(256) void spmm_kernel(const int* __restrict__ fills,
                                                   const int2* __restrict__ rec,
                                                   const void* __restrict__ emb,
                                                   float* __restrict__ out)
{
    constexpr int CAP_ = NREG_ * REGF_;
    constexpr int KR   = (REGF_ + 255) / 256;
    constexpr int NS   = NREG_ * KR;
    __shared__ int2 buf[CAP_];
    __shared__ int  cnt[RPB];
    __shared__ int  start[RPB];
    __shared__ int  sc_[RPB];

    const int tid  = threadIdx.x;
    const int lane = tid & 63;
    const int wv   = tid >> 6;                // 0..3
    const int b    = blockIdx.x;
    const int rows = min(RPB, N_NODES - b * RPB);
    const uint32_t* __restrict__ embu = (const uint32_t*)emb;
    const float2*   __restrict__ emb2 = (const float2*)emb;

    if (tid < RPB) cnt[tid] = 0;
    __syncthreads();

    int2 rc[NS];
    int  rk[NS];
    #pragma unroll
    for (int q = 0; q < NREG_; q++) {
        const int mq = min(fills[b * NREG_ + q], REGF_);
        #pragma unroll
        for (int k = 0; k < KR; k++) {
            const int slot = q * KR + k;
            const int i = k * 256 + tid;
            rk[slot] = -1;
            if (i < mq) {
                rc[slot] = rec[(size_t)b * CAP_ + q * REGF_ + i];
                rk[slot] = atomicAdd(&cnt[rc[slot].x >> 17], 1);
            }
        }
    }
    __syncthreads();
    if (tid < RPB) sc_[tid] = cnt[tid];
    __syncthreads();
    for (int off = 1; off < RPB; off <<= 1) {
        int t = 0;
        if (tid < RPB && tid >= off) t = sc_[tid - off];
        __syncthreads();
        if (tid < RPB) sc_[tid] += t;
        __syncthreads();
    }
    if (tid < RPB) start[tid] = sc_[tid] - cnt[tid];
    __syncthreads();
    #pragma unroll
    for (int slot = 0; slot < NS; slot++)
        if (rk[slot] >= 0) buf[start[rc[slot].x >> 17] + rk[slot]] = rc[slot];
    __syncthreads();

    // 4 waves x 8 rows; records row-grouped in LDS (broadcast reads)
    for (int rl = wv * 8; rl < wv * 8 + 8; rl++) {
        const int s0 = start[rl];
        const int c0 = cnt[rl];
        float ax = 0.f, ay = 0.f;
        int j = 0;
        for (; j + 8 <= c0; j += 8) {
            int2 e[8];
            #pragma unroll
            for (int q = 0; q < 8; q++) e[q] = buf[s0 + j + q];
            float mx[8], my[8], vv[8];
            #pragma unroll
            for (int q = 0; q < 8; q++) {
                int cc = e[q].x & COLMASK;
                vv[q] = __int_as_float(e[q].y);
                if (BF16) {
                    uint32_t u = embu[(size_t)cc * 64 + lane];
                    mx[q] = __uint_as_float(u << 16);
                    my[q] = __uint_as_float(u & 0xFFFF0000u);
                } else {
                    float2 mm = emb2[(size_t)cc * 64 + lane];
                    mx[q] = mm.x; my[q] = mm.y;
                }
            }
            #pragma unroll
            for (int q = 0; q < 8; q++) { ax += vv[q] * mx[q]; ay += vv[q] * my[q]; }
        }
        for (; j < c0; j++) {
            int2 e = buf[s0 + j];
            int cc = e.x & COLMASK;
            float vv = __int_as_float(e.y);
            float mx, my;
            if (BF16) {
                uint32_t u = embu[(size_t)cc * 64 + lane];
                mx = __uint_as_float(u << 16);
                my = __uint_as_float(u & 0xFFFF0000u);
            } else {
                float2 mm = emb2[(size_t)cc * 64 + lane];
                mx = mm.x; my = mm.y;
            }
            ax += vv * mx; ay += vv * my;
        }
        if (rl < rows) {
            float2* o = (float2*)(out + (size_t)(b * RPB + rl) * D_FEAT);
            o[lane] = make_float2(ax, ay);
        }
    }
}

// ============ Overflow fixup (handful of edges, exact fp32) ============
__global__ __launch_bounds__(256) void oflow_kernel(const int4* __restrict__ oflow,
                                                    const int* __restrict__ ocnt,
                                                    const float* __restrict__ embeds,
                                                    float* __restrict__ out) {
    const int nof  = min(*ocnt, OCAP);
    const int lane = threadIdx.x & 63;
    const int w    = (blockIdx.x * 256 + threadIdx.x) >> 6;
    const int nw   = (gridDim.x * 256) >> 6;
    for (int i = w; i < nof; i += nw) {
        int4 e = oflow[i];
        const float2* src = (const float2*)(embeds + (size_t)e.y * D_FEAT);
        float2 mm = src[lane];
        float vv = __int_as_float(e.z);
        float* dst = out + (size_t)e.x * D_FEAT + (lane << 1);
        unsafeAtomicAdd(dst,     vv * mm.x);
        unsafeAtomicAdd(dst + 1, vv * mm.y);
    }
}

// ============ Last-resort fallback ============
__global__ __launch_bounds__(256) void spmm_atomic_kernel(
    const int* __restrict__ edge_row, const int* __restrict__ edge_col,
    const float* __restrict__ edge_val, const float* __restrict__ embeds,
    float* __restrict__ out, int n_edges)
{
    const int lane    = threadIdx.x & 63;
    const int wave_id = (blockIdx.x * blockDim.x + threadIdx.x) >> 6;
    const int n_waves = (gridDim.x * blockDim.x) >> 6;
    for (int e = wave_id; e < n_edges; e += n_waves) {
        const int   rr = edge_row[e];
        const int   cc = edge_col[e];
        const float vv = edge_val[e];
        const float2* src = (const float2*)(embeds + (size_t)cc * D_FEAT);
        float2 mm = src[lane];
        float* dst = out + (size_t)rr * D_FEAT + (lane << 1);
        unsafeAtomicAdd(dst,     vv * mm.x);
        unsafeAtomicAdd(dst + 1, vv * mm.y);
    }
}

static inline size_t align256(size_t x) { return (x + 255) & ~(size_t)255; }

extern "C" void kernel_launch(void* const* d_in, const int* in_sizes, int n_in,
                              void* d_out, int out_size, void* d_ws, size_t ws_size,
                              hipStream_t stream) {
    const int*   edge_row = (const int*)d_in[0];
    const int*   edge_col = (const int*)d_in[1];
    const float* edge_val = (const float*)d_in[2];
    const float* embeds   = (const float*)d_in[3];
    float*       out      = (float*)d_out;

    const int n_edges = in_sizes[0];
    const int scb  = (n_edges + SC_TILE - 1) / SC_TILE;      // 196
    const int capa = scb * SEGA;                             // 40768
    const int spq  = (scb + NREG - 1) / NREG;                // 49
    const int n4   = N_NODES * (D_FEAT / 4);

    // ---- fast-tier layout ----
    size_t off = 0;
    size_t o_meta  = off; off = align256(off + 256);                         // ocnt
    size_t o_oflow = off; off = align256(off + (size_t)OCAP * 16);
    size_t o_fillF = off; off = align256(off + (size_t)NBUCKF * NREG * 4);
    size_t o_cntA  = off; off = align256(off + (size_t)NSUP * scb * 4);
    size_t o_recA  = off; off = align256(off + (size_t)NSUP * capa * 8);
    size_t o_recF  = off; off = align256(off + (size_t)NBUCKF * CAPFF * 8);
    size_t o_embF  = off; off = align256(off + (size_t)N_NODES * 64 * 4);
    const size_t need_fast = off;                                            // ~90 MB
    // ---- mid-tier layout ----
    size_t mo = 0;
    size_t m_meta  = mo; mo = align256(mo + 256);
    size_t m_oflow = mo; mo = align256(mo + (size_t)OCAP * 16);
    size_t m_cur   = mo; mo = align256(mo + (size_t)NBUCKR * 4);
    size_t m_rec   = mo; mo = align256(mo + (size_t)NBUCKR * CAPFM * 8);
    const size_t need_fp32 = mo;                                             // ~29 MB
    size_t m_emb   = mo; mo = align256(mo + (size_t)N_NODES * 64 * 4);
    const size_t need_mid = mo;                                              // ~54.6 MB

    char* ws = (char*)d_ws;

    if (ws_size >= need_fast) {
        int*      ocnt  = (int*)(ws + o_meta);
        int4*     oflow = (int4*)(ws + o_oflow);
        int*      fillF = (int*)(ws + o_fillF);
        int*      cntA  = (int*)(ws + o_cntA);
        int2*     recA  = (int2*)(ws + o_recA);
        int2*     recF  = (int2*)(ws + o_recF);
        uint32_t* embbf = (uint32_t*)(ws + o_embF);

        hipMemsetAsync(ocnt, 0, 256, stream);
        passA_kernel<true><<<dim3(scb * 2), dim3(SC_THR), 0, stream>>>(
            edge_row, edge_col, edge_val, cntA, recA, oflow, ocnt,
            (const float4*)embeds, (uint2*)embbf, n_edges, scb, capa, n4);
        passB_kernel<<<dim3(NSUP * NREG), dim3(1024), 0, stream>>>(
            cntA, recA, fillF, recF, oflow, ocnt, scb, capa, spq);
        spmm_kernel<true, NREG, REGF><<<dim3(NBUCKF), dim3(256), 0, stream>>>(
            fillF, recF, embbf, out);
        oflow_kernel<<<dim3(16), dim3(256), 0, stream>>>(oflow, ocnt, embeds, out);
    } else if (ws_size >= need_mid) {
        int*      ocnt  = (int*)(ws + m_meta);
        int4*     oflow = (int4*)(ws + m_oflow);
        int*      cur   = (int*)(ws + m_cur);
        int2*     rec   = (int2*)(ws + m_rec);
        uint32_t* embbf = (uint32_t*)(ws + m_emb);

        hipMemsetAsync(ocnt, 0, 256, stream);
        hipMemsetAsync(cur, 0, (size_t)NBUCKR * 4, stream);
        scatter_mid_kernel<true><<<dim3(scb * 2), dim3(SC_THR), 0, stream>>>(
            edge_row, edge_col, edge_val, cur, rec, oflow, ocnt,
            (const float4*)embeds, (uint2*)embbf, n_edges, scb, n4);
        spmm_kernel<true, 1, CAPFM><<<dim3(NBUCKR), dim3(256), 0, stream>>>(
            cur, rec, embbf, out);
        oflow_kernel<<<dim3(16), dim3(256), 0, stream>>>(oflow, ocnt, embeds, out);
    } else if (ws_size >= need_fp32) {
        int*  ocnt  = (int*)(ws + m_meta);
        int4* oflow = (int4*)(ws + m_oflow);
        int*  cur   = (int*)(ws + m_cur);
        int2* rec   = (int2*)(ws + m_rec);

        hipMemsetAsync(ocnt, 0, 256, stream);
        hipMemsetAsync(cur, 0, (size_t)NBUCKR * 4, stream);
        scatter_mid_kernel<false><<<dim3(scb), dim3(SC_THR), 0, stream>>>(
            edge_row, edge_col, edge_val, cur, rec, oflow, ocnt,
            (const float4*)embeds, (uint2*)nullptr, n_edges, scb, n4);
        spmm_kernel<false, 1, CAPFM><<<dim3(NBUCKR), dim3(256), 0, stream>>>(
            cur, rec, embeds, out);
        oflow_kernel<<<dim3(16), dim3(256), 0, stream>>>(oflow, ocnt, embeds, out);
    } else {
        hipMemsetAsync(out, 0, (size_t)out_size * sizeof(float), stream);
        spmm_atomic_kernel<<<dim3(4096), dim3(256), 0, stream>>>(
            edge_row, edge_col, edge_val, embeds, out, n_edges);
    }
}